// Round 1
// baseline (5539.130 us; speedup 1.0000x reference)
//
#include <hip/hip_runtime.h>
#include <math.h>

#define T_STEPS 4
#define NNODES 50000
#define NEDGES 400000
#define FIN 128   // input feature dim for both layers

__device__ __forceinline__ float sigmoidf_(float x) { return 1.0f / (1.0f + __expf(-x)); }

__device__ __forceinline__ unsigned int key_of(float s) {
    unsigned int u = __float_as_uint(s);
    return (u & 0x80000000u) ? ~u : (u | 0x80000000u);
}

// ---------------- norms of the two scorers ----------------
__global__ void norm_kernel(const float* __restrict__ s0, const float* __restrict__ s1,
                            float* __restrict__ norms) {
    __shared__ float red[128];
    int tid = threadIdx.x;  // 128 threads
    float a = s0[tid];
    red[tid] = a * a;
    __syncthreads();
    for (int off = 64; off > 0; off >>= 1) { if (tid < off) red[tid] += red[tid + off]; __syncthreads(); }
    if (tid == 0) norms[0] = sqrtf(red[0]);
    __syncthreads();
    float b = s1[tid];
    red[tid] = b * b;
    __syncthreads();
    for (int off = 64; off > 0; off >>= 1) { if (tid < off) red[tid] += red[tid + off]; __syncthreads(); }
    if (tid == 0) norms[1] = sqrtf(red[0]);
}

// ---------------- scores = X @ scorer / norm + mask ----------------
template <bool RELU>
__global__ void scores_kernel(const float* __restrict__ X, const float* __restrict__ scorer,
                              const float* __restrict__ norms, int normIdx,
                              const float* __restrict__ mask, float* __restrict__ scores, int N) {
    __shared__ float sc[FIN];
    if (threadIdx.x < FIN) sc[threadIdx.x] = scorer[threadIdx.x];
    __syncthreads();
    int n = blockIdx.x * blockDim.x + threadIdx.x;
    if (n >= N) return;
    const float4* xr = (const float4*)(X + (size_t)n * FIN);
    float acc = 0.f;
#pragma unroll 8
    for (int k4 = 0; k4 < FIN / 4; k4++) {
        float4 v = xr[k4];
        if (RELU) { v.x = fmaxf(v.x, 0.f); v.y = fmaxf(v.y, 0.f); v.z = fmaxf(v.z, 0.f); v.w = fmaxf(v.w, 0.f); }
        acc += v.x * sc[k4 * 4] + v.y * sc[k4 * 4 + 1] + v.z * sc[k4 * 4 + 2] + v.w * sc[k4 * 4 + 3];
    }
    scores[n] = acc / norms[normIdx] + mask[n];
}

// ---------------- single-block radix-select top-K + build z ----------------
// z[r*K + j] = relu?(X[idx_j * FIN + r]) * tanh(val_j), vals sorted desc, ties -> lower idx first
#define EQCAP 512
template <int K, bool RELU>
__global__ void __launch_bounds__(1024)
topk_z_kernel(const float* __restrict__ scores, const float* __restrict__ X,
              float* __restrict__ z, int N) {
    __shared__ unsigned int hist[256];
    __shared__ unsigned int s_prefix;
    __shared__ int s_need;
    __shared__ int cnt_gt, cnt_eq;
    __shared__ int sel_idx[K];
    __shared__ float sel_val[K];
    __shared__ int eq_idx[EQCAP];
    __shared__ int out_idx[K];
    __shared__ float out_tanh[K];
    int tid = threadIdx.x, bs = blockDim.x;

    if (tid == 0) { s_prefix = 0u; s_need = K; cnt_gt = 0; cnt_eq = 0; }
    __syncthreads();

    for (int shift = 24; shift >= 0; shift -= 8) {
        for (int i = tid; i < 256; i += bs) hist[i] = 0u;
        __syncthreads();
        unsigned int pfx = s_prefix;
        for (int n = tid; n < N; n += bs) {
            unsigned int key = key_of(scores[n]);
            bool match = (shift == 24) || ((key >> (shift + 8)) == pfx);
            if (match) atomicAdd(&hist[(key >> shift) & 0xFFu], 1u);
        }
        __syncthreads();
        if (tid == 0) {
            int rem = s_need;
            int b;
            for (b = 255; b >= 1; b--) {
                int h = (int)hist[b];
                if (rem > h) rem -= h; else break;
            }
            s_prefix = (s_prefix << 8) | (unsigned int)b;
            s_need = rem;
        }
        __syncthreads();
    }
    unsigned int Kstar = s_prefix;
    int need = s_need;
    __syncthreads();

    for (int n = tid; n < N; n += bs) {
        float s = scores[n];
        unsigned int key = key_of(s);
        if (key > Kstar) {
            int p = atomicAdd(&cnt_gt, 1);
            sel_idx[p] = n; sel_val[p] = s;
        } else if (key == Kstar) {
            int p = atomicAdd(&cnt_eq, 1);
            if (p < EQCAP) eq_idx[p] = n;
        }
    }
    __syncthreads();
    int g = cnt_gt;                   // == K - need
    int m = min(cnt_eq, EQCAP);
    for (int i = tid; i < m; i += bs) {
        int my = eq_idx[i];
        int rank = 0;
        for (int j = 0; j < m; j++) rank += (eq_idx[j] < my);
        if (rank < need) { sel_idx[g + rank] = my; sel_val[g + rank] = scores[my]; }
    }
    __syncthreads();
    // final stable sort (val desc, idx asc) of K entries
    if (tid < K) {
        float v = sel_val[tid];
        int id = sel_idx[tid];
        unsigned int mykey = key_of(v);
        int rank = 0;
        for (int j = 0; j < K; j++) {
            unsigned int kj = key_of(sel_val[j]);
            rank += (kj > mykey) || (kj == mykey && sel_idx[j] < id);
        }
        out_idx[rank] = id;
        out_tanh[rank] = tanhf(v);
    }
    __syncthreads();
    for (int i = tid; i < FIN * K; i += bs) {
        int r = i / K, j = i % K;
        float xv = X[(size_t)out_idx[j] * FIN + r];
        if (RELU) xv = fmaxf(xv, 0.f);
        z[i] = xv * out_tanh[j];
    }
}

// ---------------- GRU gate kernels (tiny matmuls) ----------------
template <int COLS>
__global__ void gru_gates_kernel(const float* __restrict__ z, const float* __restrict__ Q,
                                 const float* __restrict__ Wu, const float* __restrict__ Uu,
                                 const float* __restrict__ Bu, const float* __restrict__ Wr,
                                 const float* __restrict__ Ur, const float* __restrict__ Br,
                                 float* __restrict__ upd, float* __restrict__ rst) {
    int gid = blockIdx.x * blockDim.x + threadIdx.x;
    if (gid >= 128 * COLS) return;
    int r = gid / COLS, c = gid % COLS;
    float su = Bu[gid], sr = Br[gid];
#pragma unroll 4
    for (int kk = 0; kk < 128; kk++) {
        float zz = z[kk * COLS + c];
        float qq = Q[kk * COLS + c];
        su += Wu[r * 128 + kk] * zz + Uu[r * 128 + kk] * qq;
        sr += Wr[r * 128 + kk] * zz + Ur[r * 128 + kk] * qq;
    }
    upd[gid] = sigmoidf_(su);
    rst[gid] = sigmoidf_(sr);
}

template <int COLS>
__global__ void gru_update_kernel(const float* __restrict__ z, const float* __restrict__ Q,
                                  const float* __restrict__ Wh, const float* __restrict__ Uh,
                                  const float* __restrict__ Bh, const float* __restrict__ upd,
                                  const float* __restrict__ rst, float* __restrict__ Qn) {
    int gid = blockIdx.x * blockDim.x + threadIdx.x;
    if (gid >= 128 * COLS) return;
    int r = gid / COLS, c = gid % COLS;
    float s = Bh[gid];
#pragma unroll 4
    for (int kk = 0; kk < 128; kk++) {
        float zz = z[kk * COLS + c];
        float rq = rst[kk * COLS + c] * Q[kk * COLS + c];
        s += Wh[r * 128 + kk] * zz + Uh[r * 128 + kk] * rq;
    }
    float h = tanhf(s);
    float u = upd[gid];
    Qn[gid] = (1.f - u) * Q[gid] + u * h;
}

// ---------------- XW = X @ Qn  (N x 128) @ (128 x COLS) ----------------
template <int COLS, bool RELU>
__global__ void __launch_bounds__(256)
xw_kernel(const float* __restrict__ X, const float* __restrict__ Qn,
          float* __restrict__ out, int N) {
    constexpr int TPR = COLS / 4;       // threads per row (32 or 16)
    constexpr int RPG = 256 / TPR;      // rows per group (8 or 16)
    constexpr int RPB = RPG * 4;        // rows per block (32 or 64)
    __shared__ float4 qs[128 * TPR];
    for (int i = threadIdx.x; i < 128 * TPR; i += 256) qs[i] = ((const float4*)Qn)[i];
    __syncthreads();
    int lane_c = threadIdx.x % TPR;
    int rloc = threadIdx.x / TPR;
    int base = blockIdx.x * RPB;
    int rows[4];
    float4 acc[4];
#pragma unroll
    for (int j = 0; j < 4; j++) {
        rows[j] = base + rloc + j * RPG;
        acc[j] = make_float4(0.f, 0.f, 0.f, 0.f);
    }
    int nc[4];
#pragma unroll
    for (int j = 0; j < 4; j++) nc[j] = min(rows[j], N - 1);

    for (int k4 = 0; k4 < 32; k4++) {
        float4 q0 = qs[(k4 * 4 + 0) * TPR + lane_c];
        float4 q1 = qs[(k4 * 4 + 1) * TPR + lane_c];
        float4 q2 = qs[(k4 * 4 + 2) * TPR + lane_c];
        float4 q3 = qs[(k4 * 4 + 3) * TPR + lane_c];
#pragma unroll
        for (int j = 0; j < 4; j++) {
            float4 xv = ((const float4*)(X + (size_t)nc[j] * FIN))[k4];
            if (RELU) { xv.x = fmaxf(xv.x, 0.f); xv.y = fmaxf(xv.y, 0.f); xv.z = fmaxf(xv.z, 0.f); xv.w = fmaxf(xv.w, 0.f); }
            acc[j].x += xv.x * q0.x + xv.y * q1.x + xv.z * q2.x + xv.w * q3.x;
            acc[j].y += xv.x * q0.y + xv.y * q1.y + xv.z * q2.y + xv.w * q3.y;
            acc[j].z += xv.x * q0.z + xv.y * q1.z + xv.z * q2.z + xv.w * q3.z;
            acc[j].w += xv.x * q0.w + xv.y * q1.w + xv.z * q2.w + xv.w * q3.w;
        }
    }
#pragma unroll
    for (int j = 0; j < 4; j++) {
        if (rows[j] < N) ((float4*)(out + (size_t)rows[j] * COLS))[lane_c] = acc[j];
    }
}

// ---------------- edge gather-scale-scatter (segment_sum via atomics) ----------------
template <int COLS>
__global__ void scatter_kernel(const float* __restrict__ XW, const int* __restrict__ src,
                               const int* __restrict__ dst, const float* __restrict__ w,
                               float* __restrict__ out, int E) {
    constexpr int TPE = COLS / 4;
    long long gid = (long long)blockIdx.x * blockDim.x + threadIdx.x;
    int e = (int)(gid / TPE);
    int c4 = (int)(gid % TPE) * 4;
    if (e >= E) return;
    int s = src[e], d = dst[e];
    float wt = w[e];
    float4 v = *(const float4*)(XW + (size_t)s * COLS + c4);
    float* o = out + (size_t)d * COLS + c4;
    atomicAdd(o + 0, v.x * wt);
    atomicAdd(o + 1, v.y * wt);
    atomicAdd(o + 2, v.z * wt);
    atomicAdd(o + 3, v.w * wt);
}

// ---------------- final relu over d_out ----------------
__global__ void relu_kernel(float* __restrict__ p, long long n4) {
    long long i = (long long)blockIdx.x * blockDim.x + threadIdx.x;
    if (i < n4) {
        float4 v = ((float4*)p)[i];
        v.x = fmaxf(v.x, 0.f); v.y = fmaxf(v.y, 0.f); v.z = fmaxf(v.z, 0.f); v.w = fmaxf(v.w, 0.f);
        ((float4*)p)[i] = v;
    }
}

extern "C" void kernel_launch(void* const* d_in, const int* in_sizes, int n_in,
                              void* d_out, int out_size, void* d_ws, size_t ws_size,
                              hipStream_t stream) {
    const float* node_embs   = (const float*)d_in[0];
    const float* mask        = (const float*)d_in[1];
    const int*   edge_src    = (const int*)d_in[2];
    const int*   edge_dst    = (const int*)d_in[3];
    const float* edge_weight = (const float*)d_in[4];
    const float* gcn_w0      = (const float*)d_in[5];
    const float* gcn_w1      = (const float*)d_in[6];
    const float* l0p[10];
    const float* l1p[10];
    for (int i = 0; i < 10; i++) l0p[i] = (const float*)d_in[7 + i];
    for (int i = 0; i < 10; i++) l1p[i] = (const float*)d_in[17 + i];
    // l*p: 0=Wu 1=Uu 2=Bu 3=Wr 4=Ur 5=Br 6=Wh 7=Uh 8=Bh 9=scorer

    char* ws = (char*)d_ws;
    size_t off = 0;
    auto alloc = [&](size_t bytes) -> void* {
        void* p = ws + off;
        off += (bytes + 255) / 256 * 256;
        return p;
    };
    float* XWbuf = (float*)alloc((size_t)NNODES * 128 * 4);
    float* h1buf = (float*)alloc((size_t)NNODES * 128 * 4);
    float* scores = (float*)alloc((size_t)NNODES * 4);
    float* zbuf = (float*)alloc(128 * 128 * 4);
    float* Q0a = (float*)alloc(128 * 128 * 4);
    float* Q0b = (float*)alloc(128 * 128 * 4);
    float* Q1a = (float*)alloc(128 * 64 * 4);
    float* Q1b = (float*)alloc(128 * 64 * 4);
    float* updb = (float*)alloc(128 * 128 * 4);
    float* rstb = (float*)alloc(128 * 128 * 4);
    float* norms = (float*)alloc(64);

    hipMemcpyAsync(Q0a, gcn_w0, 128 * 128 * 4, hipMemcpyDeviceToDevice, stream);
    hipMemcpyAsync(Q1a, gcn_w1, 128 * 64 * 4, hipMemcpyDeviceToDevice, stream);
    hipMemsetAsync(d_out, 0, (size_t)out_size * 4, stream);
    norm_kernel<<<1, 128, 0, stream>>>(l0p[9], l1p[9], norms);

    float* Q0cur = Q0a; float* Q0nxt = Q0b;
    float* Q1cur = Q1a; float* Q1nxt = Q1b;

    for (int t = 0; t < T_STEPS; t++) {
        const float* X0 = node_embs + (size_t)t * NNODES * 128;
        const float* mk = mask + (size_t)t * NNODES;
        const int* es = edge_src + (size_t)t * NEDGES;
        const int* ed = edge_dst + (size_t)t * NEDGES;
        const float* ew = edge_weight + (size_t)t * NEDGES;

        // ---- layer 0 ----
        scores_kernel<false><<<(NNODES + 255) / 256, 256, 0, stream>>>(X0, l0p[9], norms, 0, mk, scores, NNODES);
        topk_z_kernel<128, false><<<1, 1024, 0, stream>>>(scores, X0, zbuf, NNODES);
        gru_gates_kernel<128><<<(128 * 128) / 256, 256, 0, stream>>>(zbuf, Q0cur, l0p[0], l0p[1], l0p[2], l0p[3], l0p[4], l0p[5], updb, rstb);
        gru_update_kernel<128><<<(128 * 128) / 256, 256, 0, stream>>>(zbuf, Q0cur, l0p[6], l0p[7], l0p[8], updb, rstb, Q0nxt);
        xw_kernel<128, false><<<(NNODES + 31) / 32, 256, 0, stream>>>(X0, Q0nxt, XWbuf, NNODES);
        hipMemsetAsync(h1buf, 0, (size_t)NNODES * 128 * 4, stream);
        scatter_kernel<128><<<(NEDGES * 32 + 255) / 256, 256, 0, stream>>>(XWbuf, es, ed, ew, h1buf, NEDGES);

        // ---- layer 1 (X = relu(h1buf), applied on read) ----
        scores_kernel<true><<<(NNODES + 255) / 256, 256, 0, stream>>>(h1buf, l1p[9], norms, 1, mk, scores, NNODES);
        topk_z_kernel<64, true><<<1, 1024, 0, stream>>>(scores, h1buf, zbuf, NNODES);
        gru_gates_kernel<64><<<(128 * 64) / 256, 256, 0, stream>>>(zbuf, Q1cur, l1p[0], l1p[1], l1p[2], l1p[3], l1p[4], l1p[5], updb, rstb);
        gru_update_kernel<64><<<(128 * 64) / 256, 256, 0, stream>>>(zbuf, Q1cur, l1p[6], l1p[7], l1p[8], updb, rstb, Q1nxt);
        xw_kernel<64, true><<<(NNODES + 63) / 64, 256, 0, stream>>>(h1buf, Q1nxt, XWbuf, NNODES);
        float* out_t = (float*)d_out + (size_t)t * NNODES * 64;
        scatter_kernel<64><<<(NEDGES * 16 + 255) / 256, 256, 0, stream>>>(XWbuf, es, ed, ew, out_t, NEDGES);

        float* tmp;
        tmp = Q0cur; Q0cur = Q0nxt; Q0nxt = tmp;
        tmp = Q1cur; Q1cur = Q1nxt; Q1nxt = tmp;
    }
    long long n4 = (long long)out_size / 4;
    relu_kernel<<<(unsigned int)((n4 + 255) / 256), 256, 0, stream>>>((float*)d_out, n4);
}

// Round 2
// 2347.221 us; speedup vs baseline: 2.3599x; 2.3599x over previous
//
#include <hip/hip_runtime.h>
#include <math.h>

#define T_STEPS 4
#define NNODES 50000
#define NEDGES 400000
#define FIN 128   // input feature dim for both layers

__device__ __forceinline__ float sigmoidf_(float x) { return 1.0f / (1.0f + __expf(-x)); }

__device__ __forceinline__ unsigned int key_of(float s) {
    unsigned int u = __float_as_uint(s);
    return (u & 0x80000000u) ? ~u : (u | 0x80000000u);
}

// ---------------- norms of the two scorers ----------------
__global__ void norm_kernel(const float* __restrict__ s0, const float* __restrict__ s1,
                            float* __restrict__ norms) {
    __shared__ float red[128];
    int tid = threadIdx.x;  // 128 threads
    float a = s0[tid];
    red[tid] = a * a;
    __syncthreads();
    for (int off = 64; off > 0; off >>= 1) { if (tid < off) red[tid] += red[tid + off]; __syncthreads(); }
    if (tid == 0) norms[0] = sqrtf(red[0]);
    __syncthreads();
    float b = s1[tid];
    red[tid] = b * b;
    __syncthreads();
    for (int off = 64; off > 0; off >>= 1) { if (tid < off) red[tid] += red[tid + off]; __syncthreads(); }
    if (tid == 0) norms[1] = sqrtf(red[0]);
}

// ---------------- scores = X @ scorer / norm + mask ----------------
__global__ void scores_kernel(const float* __restrict__ X, const float* __restrict__ scorer,
                              const float* __restrict__ norms, int normIdx,
                              const float* __restrict__ mask, float* __restrict__ scores, int N) {
    __shared__ float sc[FIN];
    if (threadIdx.x < FIN) sc[threadIdx.x] = scorer[threadIdx.x];
    __syncthreads();
    int n = blockIdx.x * blockDim.x + threadIdx.x;
    if (n >= N) return;
    const float4* xr = (const float4*)(X + (size_t)n * FIN);
    float acc = 0.f;
#pragma unroll 8
    for (int k4 = 0; k4 < FIN / 4; k4++) {
        float4 v = xr[k4];
        acc += v.x * sc[k4 * 4] + v.y * sc[k4 * 4 + 1] + v.z * sc[k4 * 4 + 2] + v.w * sc[k4 * 4 + 3];
    }
    scores[n] = acc / norms[normIdx] + mask[n];
}

// ---------------- single-block radix-select top-K + build z ----------------
// z[r*K + j] = X[idx_j * FIN + r] * tanh(val_j), vals sorted desc, ties -> lower idx first
#define EQCAP 512
template <int K>
__global__ void __launch_bounds__(1024)
topk_z_kernel(const float* __restrict__ scores, const float* __restrict__ X,
              float* __restrict__ z, int N) {
    __shared__ unsigned int hist[256];
    __shared__ unsigned int s_prefix;
    __shared__ int s_need;
    __shared__ int cnt_gt, cnt_eq;
    __shared__ int sel_idx[K];
    __shared__ float sel_val[K];
    __shared__ int eq_idx[EQCAP];
    __shared__ int out_idx[K];
    __shared__ float out_tanh[K];
    int tid = threadIdx.x, bs = blockDim.x;

    if (tid == 0) { s_prefix = 0u; s_need = K; cnt_gt = 0; cnt_eq = 0; }
    __syncthreads();

    for (int shift = 24; shift >= 0; shift -= 8) {
        for (int i = tid; i < 256; i += bs) hist[i] = 0u;
        __syncthreads();
        unsigned int pfx = s_prefix;
        for (int n = tid; n < N; n += bs) {
            unsigned int key = key_of(scores[n]);
            bool match = (shift == 24) || ((key >> (shift + 8)) == pfx);
            if (match) atomicAdd(&hist[(key >> shift) & 0xFFu], 1u);
        }
        __syncthreads();
        if (tid == 0) {
            int rem = s_need;
            int b;
            for (b = 255; b >= 1; b--) {
                int h = (int)hist[b];
                if (rem > h) rem -= h; else break;
            }
            s_prefix = (s_prefix << 8) | (unsigned int)b;
            s_need = rem;
        }
        __syncthreads();
    }
    unsigned int Kstar = s_prefix;
    int need = s_need;
    __syncthreads();

    for (int n = tid; n < N; n += bs) {
        float s = scores[n];
        unsigned int key = key_of(s);
        if (key > Kstar) {
            int p = atomicAdd(&cnt_gt, 1);
            sel_idx[p] = n; sel_val[p] = s;
        } else if (key == Kstar) {
            int p = atomicAdd(&cnt_eq, 1);
            if (p < EQCAP) eq_idx[p] = n;
        }
    }
    __syncthreads();
    int g = cnt_gt;                   // == K - need
    int m = min(cnt_eq, EQCAP);
    for (int i = tid; i < m; i += bs) {
        int my = eq_idx[i];
        int rank = 0;
        for (int j = 0; j < m; j++) rank += (eq_idx[j] < my);
        if (rank < need) { sel_idx[g + rank] = my; sel_val[g + rank] = scores[my]; }
    }
    __syncthreads();
    // final stable sort (val desc, idx asc) of K entries
    if (tid < K) {
        float v = sel_val[tid];
        int id = sel_idx[tid];
        unsigned int mykey = key_of(v);
        int rank = 0;
        for (int j = 0; j < K; j++) {
            unsigned int kj = key_of(sel_val[j]);
            rank += (kj > mykey) || (kj == mykey && sel_idx[j] < id);
        }
        out_idx[rank] = id;
        out_tanh[rank] = tanhf(v);
    }
    __syncthreads();
    for (int i = tid; i < FIN * K; i += bs) {
        int r = i / K, j = i % K;
        z[i] = X[(size_t)out_idx[j] * FIN + r] * out_tanh[j];
    }
}

// ---------------- GRU gate kernels (tiny matmuls) ----------------
template <int COLS>
__global__ void gru_gates_kernel(const float* __restrict__ z, const float* __restrict__ Q,
                                 const float* __restrict__ Wu, const float* __restrict__ Uu,
                                 const float* __restrict__ Bu, const float* __restrict__ Wr,
                                 const float* __restrict__ Ur, const float* __restrict__ Br,
                                 float* __restrict__ upd, float* __restrict__ rst) {
    int gid = blockIdx.x * blockDim.x + threadIdx.x;
    if (gid >= 128 * COLS) return;
    int r = gid / COLS, c = gid % COLS;
    float su = Bu[gid], sr = Br[gid];
#pragma unroll 4
    for (int kk = 0; kk < 128; kk++) {
        float zz = z[kk * COLS + c];
        float qq = Q[kk * COLS + c];
        su += Wu[r * 128 + kk] * zz + Uu[r * 128 + kk] * qq;
        sr += Wr[r * 128 + kk] * zz + Ur[r * 128 + kk] * qq;
    }
    upd[gid] = sigmoidf_(su);
    rst[gid] = sigmoidf_(sr);
}

template <int COLS>
__global__ void gru_update_kernel(const float* __restrict__ z, const float* __restrict__ Q,
                                  const float* __restrict__ Wh, const float* __restrict__ Uh,
                                  const float* __restrict__ Bh, const float* __restrict__ upd,
                                  const float* __restrict__ rst, float* __restrict__ Qn) {
    int gid = blockIdx.x * blockDim.x + threadIdx.x;
    if (gid >= 128 * COLS) return;
    int r = gid / COLS, c = gid % COLS;
    float s = Bh[gid];
#pragma unroll 4
    for (int kk = 0; kk < 128; kk++) {
        float zz = z[kk * COLS + c];
        float rq = rst[kk * COLS + c] * Q[kk * COLS + c];
        s += Wh[r * 128 + kk] * zz + Uh[r * 128 + kk] * rq;
    }
    float h = tanhf(s);
    float u = upd[gid];
    Qn[gid] = (1.f - u) * Q[gid] + u * h;
}

// ---------------- XW = X @ Qn  (N x 128) @ (128 x COLS) ----------------
template <int COLS>
__global__ void __launch_bounds__(256)
xw_kernel(const float* __restrict__ X, const float* __restrict__ Qn,
          float* __restrict__ out, int N) {
    constexpr int TPR = COLS / 4;       // threads per row (32 or 16)
    constexpr int RPG = 256 / TPR;      // rows per group (8 or 16)
    constexpr int RPB = RPG * 4;        // rows per block (32 or 64)
    __shared__ float4 qs[128 * TPR];
    for (int i = threadIdx.x; i < 128 * TPR; i += 256) qs[i] = ((const float4*)Qn)[i];
    __syncthreads();
    int lane_c = threadIdx.x % TPR;
    int rloc = threadIdx.x / TPR;
    int base = blockIdx.x * RPB;
    int rows[4];
    float4 acc[4];
#pragma unroll
    for (int j = 0; j < 4; j++) {
        rows[j] = base + rloc + j * RPG;
        acc[j] = make_float4(0.f, 0.f, 0.f, 0.f);
    }
    int nc[4];
#pragma unroll
    for (int j = 0; j < 4; j++) nc[j] = min(rows[j], N - 1);

    for (int k4 = 0; k4 < 32; k4++) {
        float4 q0 = qs[(k4 * 4 + 0) * TPR + lane_c];
        float4 q1 = qs[(k4 * 4 + 1) * TPR + lane_c];
        float4 q2 = qs[(k4 * 4 + 2) * TPR + lane_c];
        float4 q3 = qs[(k4 * 4 + 3) * TPR + lane_c];
#pragma unroll
        for (int j = 0; j < 4; j++) {
            float4 xv = ((const float4*)(X + (size_t)nc[j] * FIN))[k4];
            acc[j].x += xv.x * q0.x + xv.y * q1.x + xv.z * q2.x + xv.w * q3.x;
            acc[j].y += xv.x * q0.y + xv.y * q1.y + xv.z * q2.y + xv.w * q3.y;
            acc[j].z += xv.x * q0.z + xv.y * q1.z + xv.z * q2.z + xv.w * q3.z;
            acc[j].w += xv.x * q0.w + xv.y * q1.w + xv.z * q2.w + xv.w * q3.w;
        }
    }
#pragma unroll
    for (int j = 0; j < 4; j++) {
        if (rows[j] < N) ((float4*)(out + (size_t)rows[j] * COLS))[lane_c] = acc[j];
    }
}

// ---------------- CSR build: histogram -> scan -> bucket ----------------
__global__ void hist_kernel(const int* __restrict__ dst, int* __restrict__ hist, int E) {
    int e = blockIdx.x * blockDim.x + threadIdx.x;
    if (e < E) atomicAdd(&hist[dst[e]], 1);
}

__global__ void __launch_bounds__(1024)
scan_kernel(const int* __restrict__ hist, int* __restrict__ row_ptr,
            int* __restrict__ cursor, int N) {
    __shared__ int partial[1024];
    const int CH = 49;  // 1024*49 >= 50000
    int tid = threadIdx.x;
    int start = tid * CH;
    int s = 0;
    for (int i = 0; i < CH; i++) { int idx = start + i; if (idx < N) s += hist[idx]; }
    partial[tid] = s;
    __syncthreads();
    for (int off = 1; off < 1024; off <<= 1) {
        int v = (tid >= off) ? partial[tid - off] : 0;
        __syncthreads();
        partial[tid] += v;
        __syncthreads();
    }
    int run = (tid == 0) ? 0 : partial[tid - 1];
    for (int i = 0; i < CH; i++) {
        int idx = start + i;
        if (idx < N) {
            row_ptr[idx] = run; cursor[idx] = run;
            run += hist[idx];
        }
    }
    if (tid == 1023) row_ptr[N] = partial[1023];
}

__global__ void bucket_kernel(const int* __restrict__ src, const int* __restrict__ dst,
                              const float* __restrict__ w, int* __restrict__ cursor,
                              int* __restrict__ ssrc, float* __restrict__ sw, int E) {
    int e = blockIdx.x * blockDim.x + threadIdx.x;
    if (e >= E) return;
    int d = dst[e];
    int pos = atomicAdd(&cursor[d], 1);
    ssrc[pos] = src[e];
    sw[pos] = w[e];
}

// ---------------- CSR aggregation: out[d] = relu(sum_e w_e * XW[src_e]) ----------------
template <int COLS>
__global__ void __launch_bounds__(256)
agg_kernel(const float* __restrict__ XW, const int* __restrict__ row_ptr,
           const int* __restrict__ ssrc, const float* __restrict__ sw,
           float* __restrict__ out, int N) {
    constexpr int TPN = COLS / 4;       // threads per node (32 or 16)
    constexpr int NPB = 256 / TPN;      // nodes per block (8 or 16)
    int node = blockIdx.x * NPB + threadIdx.x / TPN;
    int lane = threadIdx.x % TPN;
    if (node >= N) return;
    int beg = row_ptr[node], end = row_ptr[node + 1];
    float4 acc = make_float4(0.f, 0.f, 0.f, 0.f);
    for (int i = beg; i < end; i++) {
        int s = ssrc[i];
        float wt = sw[i];
        float4 v = ((const float4*)(XW + (size_t)s * COLS))[lane];
        acc.x += v.x * wt; acc.y += v.y * wt; acc.z += v.z * wt; acc.w += v.w * wt;
    }
    acc.x = fmaxf(acc.x, 0.f); acc.y = fmaxf(acc.y, 0.f);
    acc.z = fmaxf(acc.z, 0.f); acc.w = fmaxf(acc.w, 0.f);
    ((float4*)(out + (size_t)node * COLS))[lane] = acc;
}

extern "C" void kernel_launch(void* const* d_in, const int* in_sizes, int n_in,
                              void* d_out, int out_size, void* d_ws, size_t ws_size,
                              hipStream_t stream) {
    const float* node_embs   = (const float*)d_in[0];
    const float* mask        = (const float*)d_in[1];
    const int*   edge_src    = (const int*)d_in[2];
    const int*   edge_dst    = (const int*)d_in[3];
    const float* edge_weight = (const float*)d_in[4];
    const float* gcn_w0      = (const float*)d_in[5];
    const float* gcn_w1      = (const float*)d_in[6];
    const float* l0p[10];
    const float* l1p[10];
    for (int i = 0; i < 10; i++) l0p[i] = (const float*)d_in[7 + i];
    for (int i = 0; i < 10; i++) l1p[i] = (const float*)d_in[17 + i];
    // l*p: 0=Wu 1=Uu 2=Bu 3=Wr 4=Ur 5=Br 6=Wh 7=Uh 8=Bh 9=scorer

    char* ws = (char*)d_ws;
    size_t off = 0;
    auto alloc = [&](size_t bytes) -> void* {
        void* p = ws + off;
        off += (bytes + 255) / 256 * 256;
        return p;
    };
    float* XWbuf  = (float*)alloc((size_t)NNODES * 128 * 4);
    float* h1buf  = (float*)alloc((size_t)NNODES * 128 * 4);
    float* scores = (float*)alloc((size_t)NNODES * 4);
    float* zbuf   = (float*)alloc(128 * 128 * 4);
    float* Q0a    = (float*)alloc(128 * 128 * 4);
    float* Q0b    = (float*)alloc(128 * 128 * 4);
    float* Q1a    = (float*)alloc(128 * 64 * 4);
    float* Q1b    = (float*)alloc(128 * 64 * 4);
    float* updb   = (float*)alloc(128 * 128 * 4);
    float* rstb   = (float*)alloc(128 * 128 * 4);
    float* norms  = (float*)alloc(64);
    int*   histb  = (int*)alloc((size_t)NNODES * 4);
    int*   rowp   = (int*)alloc((size_t)(NNODES + 1) * 4);
    int*   cursor = (int*)alloc((size_t)NNODES * 4);
    int*   ssrc   = (int*)alloc((size_t)NEDGES * 4);
    float* sww    = (float*)alloc((size_t)NEDGES * 4);

    hipMemcpyAsync(Q0a, gcn_w0, 128 * 128 * 4, hipMemcpyDeviceToDevice, stream);
    hipMemcpyAsync(Q1a, gcn_w1, 128 * 64 * 4, hipMemcpyDeviceToDevice, stream);
    norm_kernel<<<1, 128, 0, stream>>>(l0p[9], l1p[9], norms);

    float* Q0cur = Q0a; float* Q0nxt = Q0b;
    float* Q1cur = Q1a; float* Q1nxt = Q1b;

    for (int t = 0; t < T_STEPS; t++) {
        const float* X0 = node_embs + (size_t)t * NNODES * 128;
        const float* mk = mask + (size_t)t * NNODES;
        const int* es = edge_src + (size_t)t * NEDGES;
        const int* ed = edge_dst + (size_t)t * NEDGES;
        const float* ew = edge_weight + (size_t)t * NEDGES;

        // ---- build CSR (shared by both layers at this t) ----
        hipMemsetAsync(histb, 0, (size_t)NNODES * 4, stream);
        hist_kernel<<<(NEDGES + 255) / 256, 256, 0, stream>>>(ed, histb, NEDGES);
        scan_kernel<<<1, 1024, 0, stream>>>(histb, rowp, cursor, NNODES);
        bucket_kernel<<<(NEDGES + 255) / 256, 256, 0, stream>>>(es, ed, ew, cursor, ssrc, sww, NEDGES);

        // ---- layer 0 ----
        scores_kernel<<<(NNODES + 255) / 256, 256, 0, stream>>>(X0, l0p[9], norms, 0, mk, scores, NNODES);
        topk_z_kernel<128><<<1, 1024, 0, stream>>>(scores, X0, zbuf, NNODES);
        gru_gates_kernel<128><<<(128 * 128) / 256, 256, 0, stream>>>(zbuf, Q0cur, l0p[0], l0p[1], l0p[2], l0p[3], l0p[4], l0p[5], updb, rstb);
        gru_update_kernel<128><<<(128 * 128) / 256, 256, 0, stream>>>(zbuf, Q0cur, l0p[6], l0p[7], l0p[8], updb, rstb, Q0nxt);
        xw_kernel<128><<<(NNODES + 31) / 32, 256, 0, stream>>>(X0, Q0nxt, XWbuf, NNODES);
        agg_kernel<128><<<(NNODES + 7) / 8, 256, 0, stream>>>(XWbuf, rowp, ssrc, sww, h1buf, NNODES);

        // ---- layer 1 (h1buf already relu'd) ----
        scores_kernel<<<(NNODES + 255) / 256, 256, 0, stream>>>(h1buf, l1p[9], norms, 1, mk, scores, NNODES);
        topk_z_kernel<64><<<1, 1024, 0, stream>>>(scores, h1buf, zbuf, NNODES);
        gru_gates_kernel<64><<<(128 * 64) / 256, 256, 0, stream>>>(zbuf, Q1cur, l1p[0], l1p[1], l1p[2], l1p[3], l1p[4], l1p[5], updb, rstb);
        gru_update_kernel<64><<<(128 * 64) / 256, 256, 0, stream>>>(zbuf, Q1cur, l1p[6], l1p[7], l1p[8], updb, rstb, Q1nxt);
        xw_kernel<64><<<(NNODES + 63) / 64, 256, 0, stream>>>(h1buf, Q1nxt, XWbuf, NNODES);
        float* out_t = (float*)d_out + (size_t)t * NNODES * 64;
        agg_kernel<64><<<(NNODES + 15) / 16, 256, 0, stream>>>(XWbuf, rowp, ssrc, sww, out_t, NNODES);

        float* tmp;
        tmp = Q0cur; Q0cur = Q0nxt; Q0nxt = tmp;
        tmp = Q1cur; Q1cur = Q1nxt; Q1nxt = tmp;
    }
}

// Round 3
// 1695.572 us; speedup vs baseline: 3.2668x; 1.3843x over previous
//
#include <hip/hip_runtime.h>
#include <math.h>

#define T_STEPS 4
#define NNODES 50000
#define NEDGES 400000
#define FIN 128   // input feature dim for both layers
#define NBINS 8192
#define BINSHIFT 19  // 32-13

__device__ __forceinline__ float sigmoidf_(float x) { return 1.0f / (1.0f + __expf(-x)); }

__device__ __forceinline__ unsigned int key_of(float s) {
    unsigned int u = __float_as_uint(s);
    return (u & 0x80000000u) ? ~u : (u | 0x80000000u);
}

// ---------------- norms of the two scorers ----------------
__global__ void norm_kernel(const float* __restrict__ s0, const float* __restrict__ s1,
                            float* __restrict__ norms) {
    __shared__ float red[128];
    int tid = threadIdx.x;  // 128 threads
    float a = s0[tid];
    red[tid] = a * a;
    __syncthreads();
    for (int off = 64; off > 0; off >>= 1) { if (tid < off) red[tid] += red[tid + off]; __syncthreads(); }
    if (tid == 0) norms[0] = sqrtf(red[0]);
    __syncthreads();
    float b = s1[tid];
    red[tid] = b * b;
    __syncthreads();
    for (int off = 64; off > 0; off >>= 1) { if (tid < off) red[tid] += red[tid + off]; __syncthreads(); }
    if (tid == 0) norms[1] = sqrtf(red[0]);
}

// ---------------- scores = X @ scorer / norm + mask ----------------
__global__ void scores_kernel(const float* __restrict__ X, const float* __restrict__ scorer,
                              const float* __restrict__ norms, int normIdx,
                              const float* __restrict__ mask, float* __restrict__ scores, int N) {
    __shared__ float sc[FIN];
    if (threadIdx.x < FIN) sc[threadIdx.x] = scorer[threadIdx.x];
    __syncthreads();
    int n = blockIdx.x * blockDim.x + threadIdx.x;
    if (n >= N) return;
    const float4* xr = (const float4*)(X + (size_t)n * FIN);
    float acc = 0.f;
#pragma unroll 8
    for (int k4 = 0; k4 < FIN / 4; k4++) {
        float4 v = xr[k4];
        acc += v.x * sc[k4 * 4] + v.y * sc[k4 * 4 + 1] + v.z * sc[k4 * 4 + 2] + v.w * sc[k4 * 4 + 3];
    }
    scores[n] = acc / norms[normIdx] + mask[n];
}

// ---------------- multi-block top-k pipeline ----------------
// 1) global 8192-bin histogram of top-13 key bits
__global__ void topk_hist_kernel(const float* __restrict__ scores, int* __restrict__ ghist, int N) {
    int n = blockIdx.x * blockDim.x + threadIdx.x;
    if (n >= N) return;
    unsigned int key = key_of(scores[n]) >> BINSHIFT;
    atomicAdd(&ghist[key], 1);
}

// 2) find the critical bin: S(b)=sum_{j>=b} h[j]; bin b: S(b)>=K, S(b+1)<K; need=K-S(b+1)
__global__ void __launch_bounds__(1024)
topk_findbin_kernel(const int* __restrict__ ghist, int* __restrict__ meta, int K) {
    __shared__ int h[NBINS];
    __shared__ int cs[1024];
    int tid = threadIdx.x;
    for (int i = tid; i < NBINS; i += 1024) h[i] = ghist[i];
    __syncthreads();
    int s = 0;
#pragma unroll
    for (int i = 0; i < NBINS / 1024; i++) s += h[tid * (NBINS / 1024) + i];
    cs[tid] = s;
    __syncthreads();
    // suffix-inclusive scan: cs[t] = sum_{u>=t} cs_orig[u]
    for (int off = 1; off < 1024; off <<= 1) {
        int v = (tid + off < 1024) ? cs[tid + off] : 0;
        __syncthreads();
        cs[tid] += v;
        __syncthreads();
    }
    int run = (tid == 1023) ? 0 : cs[tid + 1];  // S(chunk_end)
    const int CH = NBINS / 1024;
    for (int b = tid * CH + CH - 1; b >= tid * CH; b--) {
        int Sb = run + h[b];
        if (Sb >= K && run < K) { meta[0] = b; meta[1] = K - run; }
        run = Sb;
    }
}

// 3) collect candidates
__global__ void topk_collect_kernel(const float* __restrict__ scores, const int* __restrict__ meta,
                                    int* __restrict__ cnts, int* __restrict__ gt_idx,
                                    float* __restrict__ gt_val, int* __restrict__ eq_idx,
                                    float* __restrict__ eq_val, int N) {
    int n = blockIdx.x * blockDim.x + threadIdx.x;
    if (n >= N) return;
    float sc = scores[n];
    int key = (int)(key_of(sc) >> BINSHIFT);
    int b = meta[0];
    if (key > b) {
        int p = atomicAdd(&cnts[0], 1);
        gt_idx[p] = n; gt_val[p] = sc;
    } else if (key == b) {
        int p = atomicAdd(&cnts[1], 1);
        eq_idx[p] = n; eq_val[p] = sc;
    }
}

// 4) exact rank of critical bin + final exact sort of K, emit idx + tanh(val)
#define EQLDS 2048
template <int K>
__global__ void __launch_bounds__(1024)
topk_finish_kernel(const int* __restrict__ meta, const int* __restrict__ cnts,
                   const int* __restrict__ gt_idx, const float* __restrict__ gt_val,
                   const int* __restrict__ eq_idx, const float* __restrict__ eq_val,
                   int* __restrict__ out_idx, float* __restrict__ out_tanh) {
    __shared__ int sidx[K];
    __shared__ float sval[K];
    __shared__ unsigned int ek[EQLDS];
    __shared__ int ei[EQLDS];
    int tid = threadIdx.x;
    int g = cnts[0];
    int m = cnts[1];
    int need = meta[1];
    for (int i = tid; i < g; i += 1024) { sidx[i] = gt_idx[i]; sval[i] = gt_val[i]; }
    bool use_lds = (m <= EQLDS);
    if (use_lds) {
        for (int i = tid; i < m; i += 1024) { ek[i] = key_of(eq_val[i]); ei[i] = eq_idx[i]; }
    }
    __syncthreads();
    for (int i = tid; i < m; i += 1024) {
        int myi = eq_idx[i];
        unsigned int myk = key_of(eq_val[i]);
        int rank = 0;
        if (use_lds) {
            for (int j = 0; j < m; j++)
                rank += (ek[j] > myk) || (ek[j] == myk && ei[j] < myi);
        } else {
            for (int j = 0; j < m; j++) {
                unsigned int kj = key_of(eq_val[j]);
                rank += (kj > myk) || (kj == myk && eq_idx[j] < myi);
            }
        }
        if (rank < need) { sidx[g + rank] = myi; sval[g + rank] = eq_val[i]; }
    }
    __syncthreads();
    if (tid < K) {
        float v = sval[tid];
        int id = sidx[tid];
        unsigned int myk = key_of(v);
        int rank = 0;
        for (int j = 0; j < K; j++) {
            unsigned int kj = key_of(sval[j]);
            rank += (kj > myk) || (kj == myk && sidx[j] < id);
        }
        out_idx[rank] = id;
        out_tanh[rank] = tanhf(v);
    }
}

// 5) z[r*K + j] = X[idx_j*FIN + r] * tanh_j   (coalesced X reads: r fastest)
template <int K>
__global__ void zbuild_kernel(const float* __restrict__ X, const int* __restrict__ out_idx,
                              const float* __restrict__ out_tanh, float* __restrict__ z) {
    int i = blockIdx.x * blockDim.x + threadIdx.x;
    if (i >= FIN * K) return;
    int j = i / FIN, r = i % FIN;
    z[r * K + j] = X[(size_t)out_idx[j] * FIN + r] * out_tanh[j];
}

// ---------------- GRU gate kernels (tiny matmuls) ----------------
template <int COLS>
__global__ void gru_gates_kernel(const float* __restrict__ z, const float* __restrict__ Q,
                                 const float* __restrict__ Wu, const float* __restrict__ Uu,
                                 const float* __restrict__ Bu, const float* __restrict__ Wr,
                                 const float* __restrict__ Ur, const float* __restrict__ Br,
                                 float* __restrict__ upd, float* __restrict__ rst) {
    int gid = blockIdx.x * blockDim.x + threadIdx.x;
    if (gid >= 128 * COLS) return;
    int r = gid / COLS, c = gid % COLS;
    float su = Bu[gid], sr = Br[gid];
#pragma unroll 4
    for (int kk = 0; kk < 128; kk++) {
        float zz = z[kk * COLS + c];
        float qq = Q[kk * COLS + c];
        su += Wu[r * 128 + kk] * zz + Uu[r * 128 + kk] * qq;
        sr += Wr[r * 128 + kk] * zz + Ur[r * 128 + kk] * qq;
    }
    upd[gid] = sigmoidf_(su);
    rst[gid] = sigmoidf_(sr);
}

template <int COLS>
__global__ void gru_update_kernel(const float* __restrict__ z, const float* __restrict__ Q,
                                  const float* __restrict__ Wh, const float* __restrict__ Uh,
                                  const float* __restrict__ Bh, const float* __restrict__ upd,
                                  const float* __restrict__ rst, float* __restrict__ Qn) {
    int gid = blockIdx.x * blockDim.x + threadIdx.x;
    if (gid >= 128 * COLS) return;
    int r = gid / COLS, c = gid % COLS;
    float s = Bh[gid];
#pragma unroll 4
    for (int kk = 0; kk < 128; kk++) {
        float zz = z[kk * COLS + c];
        float rq = rst[kk * COLS + c] * Q[kk * COLS + c];
        s += Wh[r * 128 + kk] * zz + Uh[r * 128 + kk] * rq;
    }
    float h = tanhf(s);
    float u = upd[gid];
    Qn[gid] = (1.f - u) * Q[gid] + u * h;
}

// ---------------- XW = X @ Qn  (N x 128) @ (128 x COLS) ----------------
template <int COLS>
__global__ void __launch_bounds__(256)
xw_kernel(const float* __restrict__ X, const float* __restrict__ Qn,
          float* __restrict__ out, int N) {
    constexpr int TPR = COLS / 4;       // threads per row (32 or 16)
    constexpr int RPG = 256 / TPR;      // rows per group (8 or 16)
    constexpr int RPB = RPG * 4;        // rows per block (32 or 64)
    __shared__ float4 qs[128 * TPR];
    for (int i = threadIdx.x; i < 128 * TPR; i += 256) qs[i] = ((const float4*)Qn)[i];
    __syncthreads();
    int lane_c = threadIdx.x % TPR;
    int rloc = threadIdx.x / TPR;
    int base = blockIdx.x * RPB;
    int rows[4];
    float4 acc[4];
#pragma unroll
    for (int j = 0; j < 4; j++) {
        rows[j] = base + rloc + j * RPG;
        acc[j] = make_float4(0.f, 0.f, 0.f, 0.f);
    }
    int nc[4];
#pragma unroll
    for (int j = 0; j < 4; j++) nc[j] = min(rows[j], N - 1);

    for (int k4 = 0; k4 < 32; k4++) {
        float4 q0 = qs[(k4 * 4 + 0) * TPR + lane_c];
        float4 q1 = qs[(k4 * 4 + 1) * TPR + lane_c];
        float4 q2 = qs[(k4 * 4 + 2) * TPR + lane_c];
        float4 q3 = qs[(k4 * 4 + 3) * TPR + lane_c];
#pragma unroll
        for (int j = 0; j < 4; j++) {
            float4 xv = ((const float4*)(X + (size_t)nc[j] * FIN))[k4];
            acc[j].x += xv.x * q0.x + xv.y * q1.x + xv.z * q2.x + xv.w * q3.x;
            acc[j].y += xv.x * q0.y + xv.y * q1.y + xv.z * q2.y + xv.w * q3.y;
            acc[j].z += xv.x * q0.z + xv.y * q1.z + xv.z * q2.z + xv.w * q3.z;
            acc[j].w += xv.x * q0.w + xv.y * q1.w + xv.z * q2.w + xv.w * q3.w;
        }
    }
#pragma unroll
    for (int j = 0; j < 4; j++) {
        if (rows[j] < N) ((float4*)(out + (size_t)rows[j] * COLS))[lane_c] = acc[j];
    }
}

// ---------------- CSR build: histogram -> multi-block scan -> bucket ----------------
__global__ void hist_kernel(const int* __restrict__ dst, int* __restrict__ hist, int E) {
    int e = blockIdx.x * blockDim.x + threadIdx.x;
    if (e < E) atomicAdd(&hist[dst[e]], 1);
}

__global__ void __launch_bounds__(256)
scanA_kernel(const int* __restrict__ hist, int* __restrict__ incl, int* __restrict__ bsum, int N) {
    __shared__ int sh[256];
    int gid = blockIdx.x * 256 + threadIdx.x;
    int v = (gid < N) ? hist[gid] : 0;
    sh[threadIdx.x] = v;
    __syncthreads();
    for (int off = 1; off < 256; off <<= 1) {
        int u = (threadIdx.x >= off) ? sh[threadIdx.x - off] : 0;
        __syncthreads();
        sh[threadIdx.x] += u;
        __syncthreads();
    }
    if (gid < N) incl[gid] = sh[threadIdx.x];
    if (threadIdx.x == 255) bsum[blockIdx.x] = sh[255];
}

__global__ void __launch_bounds__(256)
scanB_kernel(int* __restrict__ bsum, int nb) {
    __shared__ int sh[256];
    int tid = threadIdx.x;
    int v = (tid < nb) ? bsum[tid] : 0;
    sh[tid] = v;
    __syncthreads();
    for (int off = 1; off < 256; off <<= 1) {
        int u = (tid >= off) ? sh[tid - off] : 0;
        __syncthreads();
        sh[tid] += u;
        __syncthreads();
    }
    if (tid < nb) bsum[tid] = (tid == 0) ? 0 : sh[tid - 1];
}

__global__ void __launch_bounds__(256)
scanC_kernel(const int* __restrict__ hist, const int* __restrict__ incl,
             const int* __restrict__ bsum, int* __restrict__ row_ptr,
             int* __restrict__ cursor, int N) {
    int gid = blockIdx.x * 256 + threadIdx.x;
    if (gid < N) {
        int inc = incl[gid] + bsum[gid / 256];
        int ex = inc - hist[gid];
        row_ptr[gid] = ex;
        cursor[gid] = ex;
        if (gid == N - 1) row_ptr[N] = inc;
    }
}

__global__ void bucket_kernel(const int* __restrict__ src, const int* __restrict__ dst,
                              const float* __restrict__ w, int* __restrict__ cursor,
                              int* __restrict__ ssrc, float* __restrict__ sw, int E) {
    int e = blockIdx.x * blockDim.x + threadIdx.x;
    if (e >= E) return;
    int d = dst[e];
    int pos = atomicAdd(&cursor[d], 1);
    ssrc[pos] = src[e];
    sw[pos] = w[e];
}

// ---------------- CSR aggregation: out[d] = relu(sum_e w_e * XW[src_e]) ----------------
template <int COLS>
__global__ void __launch_bounds__(256)
agg_kernel(const float* __restrict__ XW, const int* __restrict__ row_ptr,
           const int* __restrict__ ssrc, const float* __restrict__ sw,
           float* __restrict__ out, int N) {
    constexpr int TPN = COLS / 4;       // threads per node (32 or 16)
    constexpr int NPB = 256 / TPN;      // nodes per block (8 or 16)
    int node = blockIdx.x * NPB + threadIdx.x / TPN;
    int lane = threadIdx.x % TPN;
    if (node >= N) return;
    int beg = row_ptr[node], end = row_ptr[node + 1];
    float4 acc = make_float4(0.f, 0.f, 0.f, 0.f);
    for (int i = beg; i < end; i++) {
        int s = ssrc[i];
        float wt = sw[i];
        float4 v = ((const float4*)(XW + (size_t)s * COLS))[lane];
        acc.x += v.x * wt; acc.y += v.y * wt; acc.z += v.z * wt; acc.w += v.w * wt;
    }
    acc.x = fmaxf(acc.x, 0.f); acc.y = fmaxf(acc.y, 0.f);
    acc.z = fmaxf(acc.z, 0.f); acc.w = fmaxf(acc.w, 0.f);
    ((float4*)(out + (size_t)node * COLS))[lane] = acc;
}

extern "C" void kernel_launch(void* const* d_in, const int* in_sizes, int n_in,
                              void* d_out, int out_size, void* d_ws, size_t ws_size,
                              hipStream_t stream) {
    const float* node_embs   = (const float*)d_in[0];
    const float* mask        = (const float*)d_in[1];
    const int*   edge_src    = (const int*)d_in[2];
    const int*   edge_dst    = (const int*)d_in[3];
    const float* edge_weight = (const float*)d_in[4];
    const float* gcn_w0      = (const float*)d_in[5];
    const float* gcn_w1      = (const float*)d_in[6];
    const float* l0p[10];
    const float* l1p[10];
    for (int i = 0; i < 10; i++) l0p[i] = (const float*)d_in[7 + i];
    for (int i = 0; i < 10; i++) l1p[i] = (const float*)d_in[17 + i];
    // l*p: 0=Wu 1=Uu 2=Bu 3=Wr 4=Ur 5=Br 6=Wh 7=Uh 8=Bh 9=scorer

    char* ws = (char*)d_ws;
    size_t off = 0;
    auto alloc = [&](size_t bytes) -> void* {
        void* p = ws + off;
        off += (bytes + 255) / 256 * 256;
        return p;
    };
    float* XWbuf  = (float*)alloc((size_t)NNODES * 128 * 4);
    float* h1buf  = (float*)alloc((size_t)NNODES * 128 * 4);
    float* scores = (float*)alloc((size_t)NNODES * 4);
    float* zbuf   = (float*)alloc(128 * 128 * 4);
    float* Q0a    = (float*)alloc(128 * 128 * 4);
    float* Q0b    = (float*)alloc(128 * 128 * 4);
    float* Q1a    = (float*)alloc(128 * 64 * 4);
    float* Q1b    = (float*)alloc(128 * 64 * 4);
    float* updb   = (float*)alloc(128 * 128 * 4);
    float* rstb   = (float*)alloc(128 * 128 * 4);
    float* norms  = (float*)alloc(64);
    int*   histb  = (int*)alloc((size_t)NNODES * 4);
    int*   inclb  = (int*)alloc((size_t)NNODES * 4);
    int*   bsumb  = (int*)alloc(256 * 4);
    int*   rowp   = (int*)alloc((size_t)(NNODES + 1) * 4);
    int*   cursor = (int*)alloc((size_t)NNODES * 4);
    int*   ssrc   = (int*)alloc((size_t)NEDGES * 4);
    float* sww    = (float*)alloc((size_t)NEDGES * 4);
    int*   ghist  = (int*)alloc((size_t)(NBINS + 64) * 4);   // +cnts[2] appended
    int*   cnts   = ghist + NBINS;
    int*   meta   = (int*)alloc(64);
    int*   gt_idx = (int*)alloc(128 * 4);
    float* gt_val = (float*)alloc(128 * 4);
    int*   eq_idx = (int*)alloc((size_t)NNODES * 4);
    float* eq_val = (float*)alloc((size_t)NNODES * 4);
    int*   tk_idx = (int*)alloc(128 * 4);
    float* tk_tanh= (float*)alloc(128 * 4);

    hipMemcpyAsync(Q0a, gcn_w0, 128 * 128 * 4, hipMemcpyDeviceToDevice, stream);
    hipMemcpyAsync(Q1a, gcn_w1, 128 * 64 * 4, hipMemcpyDeviceToDevice, stream);
    norm_kernel<<<1, 128, 0, stream>>>(l0p[9], l1p[9], norms);

    float* Q0cur = Q0a; float* Q0nxt = Q0b;
    float* Q1cur = Q1a; float* Q1nxt = Q1b;
    const int NB = (NNODES + 255) / 256;   // 196 blocks for scans

    for (int t = 0; t < T_STEPS; t++) {
        const float* X0 = node_embs + (size_t)t * NNODES * 128;
        const float* mk = mask + (size_t)t * NNODES;
        const int* es = edge_src + (size_t)t * NEDGES;
        const int* ed = edge_dst + (size_t)t * NEDGES;
        const float* ew = edge_weight + (size_t)t * NEDGES;

        // ---- build CSR (shared by both layers at this t) ----
        hipMemsetAsync(histb, 0, (size_t)NNODES * 4, stream);
        hist_kernel<<<(NEDGES + 255) / 256, 256, 0, stream>>>(ed, histb, NEDGES);
        scanA_kernel<<<NB, 256, 0, stream>>>(histb, inclb, bsumb, NNODES);
        scanB_kernel<<<1, 256, 0, stream>>>(bsumb, NB);
        scanC_kernel<<<NB, 256, 0, stream>>>(histb, inclb, bsumb, rowp, cursor, NNODES);
        bucket_kernel<<<(NEDGES + 255) / 256, 256, 0, stream>>>(es, ed, ew, cursor, ssrc, sww, NEDGES);

        // ---- layer 0 ----
        scores_kernel<<<NB, 256, 0, stream>>>(X0, l0p[9], norms, 0, mk, scores, NNODES);
        hipMemsetAsync(ghist, 0, (NBINS + 2) * 4, stream);
        topk_hist_kernel<<<NB, 256, 0, stream>>>(scores, ghist, NNODES);
        topk_findbin_kernel<<<1, 1024, 0, stream>>>(ghist, meta, 128);
        topk_collect_kernel<<<NB, 256, 0, stream>>>(scores, meta, cnts, gt_idx, gt_val, eq_idx, eq_val, NNODES);
        topk_finish_kernel<128><<<1, 1024, 0, stream>>>(meta, cnts, gt_idx, gt_val, eq_idx, eq_val, tk_idx, tk_tanh);
        zbuild_kernel<128><<<(FIN * 128 + 255) / 256, 256, 0, stream>>>(X0, tk_idx, tk_tanh, zbuf);
        gru_gates_kernel<128><<<(128 * 128) / 256, 256, 0, stream>>>(zbuf, Q0cur, l0p[0], l0p[1], l0p[2], l0p[3], l0p[4], l0p[5], updb, rstb);
        gru_update_kernel<128><<<(128 * 128) / 256, 256, 0, stream>>>(zbuf, Q0cur, l0p[6], l0p[7], l0p[8], updb, rstb, Q0nxt);
        xw_kernel<128><<<(NNODES + 31) / 32, 256, 0, stream>>>(X0, Q0nxt, XWbuf, NNODES);
        agg_kernel<128><<<(NNODES + 7) / 8, 256, 0, stream>>>(XWbuf, rowp, ssrc, sww, h1buf, NNODES);

        // ---- layer 1 (h1buf already relu'd) ----
        scores_kernel<<<NB, 256, 0, stream>>>(h1buf, l1p[9], norms, 1, mk, scores, NNODES);
        hipMemsetAsync(ghist, 0, (NBINS + 2) * 4, stream);
        topk_hist_kernel<<<NB, 256, 0, stream>>>(scores, ghist, NNODES);
        topk_findbin_kernel<<<1, 1024, 0, stream>>>(ghist, meta, 64);
        topk_collect_kernel<<<NB, 256, 0, stream>>>(scores, meta, cnts, gt_idx, gt_val, eq_idx, eq_val, NNODES);
        topk_finish_kernel<64><<<1, 1024, 0, stream>>>(meta, cnts, gt_idx, gt_val, eq_idx, eq_val, tk_idx, tk_tanh);
        zbuild_kernel<64><<<(FIN * 64 + 255) / 256, 256, 0, stream>>>(h1buf, tk_idx, tk_tanh, zbuf);
        gru_gates_kernel<64><<<(128 * 64) / 256, 256, 0, stream>>>(zbuf, Q1cur, l1p[0], l1p[1], l1p[2], l1p[3], l1p[4], l1p[5], updb, rstb);
        gru_update_kernel<64><<<(128 * 64) / 256, 256, 0, stream>>>(zbuf, Q1cur, l1p[6], l1p[7], l1p[8], updb, rstb, Q1nxt);
        xw_kernel<64><<<(NNODES + 63) / 64, 256, 0, stream>>>(h1buf, Q1nxt, XWbuf, NNODES);
        float* out_t = (float*)d_out + (size_t)t * NNODES * 64;
        agg_kernel<64><<<(NNODES + 15) / 16, 256, 0, stream>>>(XWbuf, rowp, ssrc, sww, out_t, NNODES);

        float* tmp;
        tmp = Q0cur; Q0cur = Q0nxt; Q0nxt = tmp;
        tmp = Q1cur; Q1cur = Q1nxt; Q1nxt = tmp;
    }
}